// Round 1
// baseline (526.334 us; speedup 1.0000x reference)
//
#include <hip/hip_runtime.h>
#include <cstdint>
#include <cmath>

#define NB 16
#define AANCH 16320
#define NCLS 80
#define KPRE 1000
#define MAXDET 300
#define NWORDS 16         // ceil(1000/64)
#define CANDCAP 16384

// logit(0.05) = ln(0.05/0.95) = -2.9444389791664403
#define THR_LOGIT -2.9444389791664403f

// ---------------- K1: per-anchor max-logit/argmax -> sortable key ----------------
__global__ void k_score(const float* __restrict__ cls, uint32_t* __restrict__ key,
                        int* __restrict__ label) {
    int a = blockIdx.x * blockDim.x + threadIdx.x;
    int b = blockIdx.y;
    if (a >= AANCH) return;
    const float4* p4 = (const float4*)(cls + ((size_t)b * AANCH + a) * NCLS);
    float best = -1e30f; int bi = 0;
#pragma unroll
    for (int c4 = 0; c4 < NCLS / 4; ++c4) {
        float4 v = p4[c4];
        if (v.x > best) { best = v.x; bi = c4 * 4 + 0; }
        if (v.y > best) { best = v.y; bi = c4 * 4 + 1; }
        if (v.z > best) { best = v.z; bi = c4 * 4 + 2; }
        if (v.w > best) { best = v.w; bi = c4 * 4 + 3; }
    }
    uint32_t k = 0;
    if (best > THR_LOGIT) {
        uint32_t ub = __float_as_uint(best);
        k = (ub & 0x80000000u) ? ~ub : (ub | 0x80000000u);  // order-preserving map
    }
    key[(size_t)b * AANCH + a] = k;
    label[(size_t)b * AANCH + a] = bi;
}

// ---------------- K2: per-image pivot selection via 13-bit histogram ----------------
__global__ void k_pivot(const uint32_t* __restrict__ key, uint32_t* __restrict__ pivot,
                        uint32_t* __restrict__ validCount, uint32_t* __restrict__ candCount) {
    __shared__ uint32_t hist[8192];
    __shared__ uint32_t part[256];
    int b = blockIdx.x, tid = threadIdx.x;
    for (int i = tid; i < 8192; i += 256) hist[i] = 0;
    __syncthreads();
    const uint32_t* kb = key + (size_t)b * AANCH;
    for (int i = tid; i < AANCH; i += 256) atomicAdd(&hist[kb[i] >> 19], 1u);
    __syncthreads();
    uint32_t s = 0;
    for (int i = 0; i < 32; ++i) s += hist[tid * 32 + i];
    part[tid] = s;
    __syncthreads();
    if (tid == 0) {
        uint32_t acc = 0; int tc = 0;
        for (int t = 255; t >= 0; --t) {
            if (acc + part[t] >= (uint32_t)KPRE) { tc = t; break; }
            acc += part[t];
        }
        uint32_t p1 = 0;
        for (int bin = tc * 32 + 31; bin >= tc * 32; --bin) {
            if (acc + hist[bin] >= (uint32_t)KPRE) { p1 = (uint32_t)bin; break; }
            acc += hist[bin];
        }
        pivot[b] = p1;
        uint32_t nvalid = (uint32_t)AANCH - hist[0];   // bin 0 holds exactly the key==0 entries
        validCount[b] = nvalid < (uint32_t)KPRE ? nvalid : (uint32_t)KPRE;
        candCount[b] = 0;
    }
}

// ---------------- K3: compact candidates with prefix >= pivot ----------------
__global__ void k_compact(const uint32_t* __restrict__ key, const uint32_t* __restrict__ pivot,
                          uint32_t* __restrict__ candCount, uint32_t* __restrict__ candKey,
                          uint32_t* __restrict__ candIdx) {
    int a = blockIdx.x * blockDim.x + threadIdx.x;
    int b = blockIdx.y;
    if (a >= AANCH) return;
    uint32_t k = key[(size_t)b * AANCH + a];
    if ((k >> 19) >= pivot[b]) {
        uint32_t pos = atomicAdd(&candCount[b], 1u);
        candKey[(size_t)b * CANDCAP + pos] = k;
        candIdx[(size_t)b * CANDCAP + pos] = (uint32_t)a;
    }
}

// ---------------- K4: exact rank of candidates (key desc, idx asc) ----------------
__global__ __launch_bounds__(1024) void k_rank(const uint32_t* __restrict__ candKey,
                                               const uint32_t* __restrict__ candIdx,
                                               const uint32_t* __restrict__ candCount,
                                               uint32_t* __restrict__ topKey,
                                               uint32_t* __restrict__ topIdx) {
    __shared__ uint32_t tk[2048];
    __shared__ uint32_t ti[2048];
    int b = blockIdx.x, tid = threadIdx.x;
    int C = (int)candCount[b];
    const uint32_t* ck = candKey + (size_t)b * CANDCAP;
    const uint32_t* ci = candIdx + (size_t)b * CANDCAP;
    for (int base = 0; base < C; base += 2048) {
        int i0 = base + tid, i1 = base + tid + 1024;
        bool h0 = i0 < C, h1 = i1 < C;
        uint32_t mk0 = 0, mi0 = 0, mk1 = 0, mi1 = 0;
        if (h0) { mk0 = ck[i0]; mi0 = ci[i0]; }
        if (h1) { mk1 = ck[i1]; mi1 = ci[i1]; }
        uint32_t r0 = 0, r1 = 0;
        for (int t0 = 0; t0 < C; t0 += 2048) {
            int n = C - t0; if (n > 2048) n = 2048;
            __syncthreads();
            for (int j = tid; j < n; j += 1024) { tk[j] = ck[t0 + j]; ti[j] = ci[t0 + j]; }
            __syncthreads();
            for (int j = 0; j < n; ++j) {
                uint32_t kj = tk[j], ij = ti[j];
                r0 += (kj > mk0) || (kj == mk0 && ij < mi0);
                r1 += (kj > mk1) || (kj == mk1 && ij < mi1);
            }
        }
        if (h0 && r0 < (uint32_t)KPRE) { topKey[b * KPRE + r0] = mk0; topIdx[b * KPRE + r0] = mi0; }
        if (h1 && r1 < (uint32_t)KPRE) { topKey[b * KPRE + r1] = mk1; topIdx[b * KPRE + r1] = mi1; }
    }
}

// ---------------- K5: gather + decode top-1000 ----------------
__global__ void k_gather(const uint32_t* __restrict__ topKey, const uint32_t* __restrict__ topIdx,
                         const int* __restrict__ label, const float* __restrict__ boxp,
                         const float* __restrict__ anchors, float4* __restrict__ topBox,
                         float* __restrict__ topScore, int* __restrict__ topLabel) {
    int t = blockIdx.x * blockDim.x + threadIdx.x;
    if (t >= NB * KPRE) return;
    int b = t / KPRE;
    uint32_t key = topKey[t];
    uint32_t idx = topIdx[t];
    const float* an = anchors + (size_t)idx * 4;
    float a0 = an[0], a1 = an[1], a2 = an[2], a3 = an[3];
    const float* dp = boxp + ((size_t)b * AANCH + idx) * 4;
    float d0 = dp[0], d1 = dp[1], d2 = dp[2], d3 = dp[3];
    float aw = a2 - a0, ah = a3 - a1;
    float acx = a0 + 0.5f * aw, acy = a1 + 0.5f * ah;
    float cx = d0 * aw + acx, cy = d1 * ah + acy;
    float w = expf(d2) * aw, h = expf(d3) * ah;
    float x1 = cx - 0.5f * w, y1 = cy - 0.5f * h;
    float x2 = cx + 0.5f * w, y2 = cy + 0.5f * h;
    x1 = fminf(fmaxf(x1, 0.0f), 512.0f);
    y1 = fminf(fmaxf(y1, 0.0f), 512.0f);
    x2 = fminf(fmaxf(x2, 0.0f), 512.0f);
    y2 = fminf(fmaxf(y2, 0.0f), 512.0f);
    float score;
    if (key == 0u) {
        score = -1.0f;
    } else {
        uint32_t ub = (key & 0x80000000u) ? (key ^ 0x80000000u) : ~key;
        float lg = __uint_as_float(ub);
        score = 1.0f / (1.0f + expf(-lg));
    }
    topBox[t] = make_float4(x1, y1, x2, y2);
    topScore[t] = score;
    topLabel[t] = label[(size_t)b * AANCH + idx];
}

// ---------------- K6: suppression bitmask matrix ----------------
__global__ __launch_bounds__(1024) void k_mask(const float4* __restrict__ topBox,
                                               const int* __restrict__ topLabel,
                                               unsigned long long* __restrict__ mask) {
    __shared__ float4 ob[KPRE];
    __shared__ float ar[KPRE];
    int b = blockIdx.x, tid = threadIdx.x;
    if (tid < KPRE) {
        float4 v = topBox[b * KPRE + tid];
        float off = (float)topLabel[b * KPRE + tid] * 10000.0f;
        v.x += off; v.y += off; v.z += off; v.w += off;
        ob[tid] = v;
        ar[tid] = fmaxf(v.z - v.x, 0.0f) * fmaxf(v.w - v.y, 0.0f);
    }
    __syncthreads();
    int i = tid;
    if (i >= KPRE) return;
    float4 bi = ob[i];
    float ai = ar[i];
    unsigned long long* row = mask + ((size_t)b * KPRE + i) * NWORDS;
    for (int wd = 0; wd < NWORDS; ++wd) {
        unsigned long long bits = 0;
        int j0 = wd * 64;
        int jend = KPRE - j0; if (jend > 64) jend = 64;
        if (j0 + 63 > i) {  // whole word <= i contributes nothing
            for (int jj = 0; jj < jend; ++jj) {
                int j = j0 + jj;
                if (j <= i) continue;
                float4 bj = ob[j];
                float ltx = fmaxf(bi.x, bj.x), lty = fmaxf(bi.y, bj.y);
                float rbx = fminf(bi.z, bj.z), rby = fminf(bi.w, bj.w);
                float wx = fmaxf(rbx - ltx, 0.0f), wy = fmaxf(rby - lty, 0.0f);
                float inter = wx * wy;
                float iou = inter / fmaxf(ai + ar[j] - inter, 1e-6f);
                if (iou > 0.5f) bits |= 1ull << jj;
            }
        }
        row[wd] = bits;
    }
}

// ---------------- K7: per-image sequential NMS sweep (1 wave/image) ----------------
__device__ inline unsigned long long shfl_u64(unsigned long long v, int lane) {
    int lo = __shfl((int)(v & 0xffffffffull), lane, 64);
    int hi = __shfl((int)(v >> 32), lane, 64);
    return ((unsigned long long)(unsigned int)hi << 32) | (unsigned int)lo;
}

__global__ void k_nms(const unsigned long long* __restrict__ mask,
                      const uint32_t* __restrict__ validCount,
                      int* __restrict__ keepList, int* __restrict__ keepCount) {
    int b = blockIdx.x, lane = threadIdx.x;  // 64 threads = 1 wave
    int V = (int)validCount[b];
    const unsigned long long* mb = mask + (size_t)b * KPRE * NWORDS;
    unsigned long long remv = 0;
    int count = 0;
    int* kl = keepList + b * MAXDET;
#define LDROW(I) ((lane < NWORDS && (I) < KPRE) ? mb[(size_t)(I) * NWORDS + lane] : 0ull)
    unsigned long long r0 = LDROW(0), r1 = LDROW(1), r2 = LDROW(2), r3 = LDROW(3);
    for (int i = 0; i < V; ++i) {
        unsigned long long row = r0; r0 = r1; r1 = r2; r2 = r3; r3 = LDROW(i + 4);
        unsigned long long w = shfl_u64(remv, i >> 6);
        bool sup = (w >> (i & 63)) & 1ull;
        if (!sup) {
            if (lane == 0) kl[count] = i;
            ++count;
            remv |= row;
            if (count >= MAXDET) break;
        }
    }
#undef LDROW
    if (lane == 0) keepCount[b] = count;
}

// ---------------- K8: write outputs ----------------
__global__ void k_out(const int* __restrict__ keepList, const int* __restrict__ keepCount,
                      const float4* __restrict__ topBox, const float* __restrict__ topScore,
                      const int* __restrict__ topLabel, float* __restrict__ out) {
    int t = blockIdx.x * blockDim.x + threadIdx.x;
    if (t >= NB * MAXDET) return;
    int b = t / MAXDET, k = t % MAXDET;
    float4 box = make_float4(0.f, 0.f, 0.f, 0.f);
    float sc = 0.0f, lb = 0.0f;
    int cnt = keepCount[b];
    if (k < cnt) {
        int i = keepList[b * MAXDET + k];
        box = topBox[b * KPRE + i];
        sc = topScore[b * KPRE + i];
        lb = (float)(topLabel[b * KPRE + i] + 1);
    }
    float* ob = out + (size_t)t * 4;
    ob[0] = box.x; ob[1] = box.y; ob[2] = box.z; ob[3] = box.w;
    out[(size_t)NB * MAXDET * 4 + t] = sc;
    out[(size_t)NB * MAXDET * 4 + (size_t)NB * MAXDET + t] = lb;
}

extern "C" void kernel_launch(void* const* d_in, const int* in_sizes, int n_in,
                              void* d_out, int out_size, void* d_ws, size_t ws_size,
                              hipStream_t stream) {
    const float* cls = (const float*)d_in[0];
    const float* boxp = (const float*)d_in[1];
    const float* anchors = (const float*)d_in[2];
    float* out = (float*)d_out;

    // workspace carve-up (all 256B aligned)
    char* wsp = (char*)d_ws;
    size_t off = 0;
    auto carve = [&](size_t bytes) -> void* {
        void* p = wsp + off;
        off += (bytes + 255) & ~(size_t)255;
        return p;
    };
    unsigned long long* mask = (unsigned long long*)carve((size_t)NB * KPRE * NWORDS * 8 + 1024);
    uint32_t* key       = (uint32_t*)carve((size_t)NB * AANCH * 4);
    int*      label     = (int*)carve((size_t)NB * AANCH * 4);
    uint32_t* candKey   = (uint32_t*)carve((size_t)NB * CANDCAP * 4);
    uint32_t* candIdx   = (uint32_t*)carve((size_t)NB * CANDCAP * 4);
    float4*   topBox    = (float4*)carve((size_t)NB * KPRE * 16);
    uint32_t* topKey    = (uint32_t*)carve((size_t)NB * KPRE * 4);
    uint32_t* topIdx    = (uint32_t*)carve((size_t)NB * KPRE * 4);
    float*    topScore  = (float*)carve((size_t)NB * KPRE * 4);
    int*      topLabel  = (int*)carve((size_t)NB * KPRE * 4);
    int*      keepList  = (int*)carve((size_t)NB * MAXDET * 4);
    int*      keepCount = (int*)carve((size_t)NB * 4);
    uint32_t* pivot     = (uint32_t*)carve((size_t)NB * 4);
    uint32_t* validCnt  = (uint32_t*)carve((size_t)NB * 4);
    uint32_t* candCount = (uint32_t*)carve((size_t)NB * 4);
    (void)ws_size; (void)out_size; (void)n_in; (void)in_sizes;

    dim3 gA((AANCH + 255) / 256, NB);
    k_score<<<gA, 256, 0, stream>>>(cls, key, label);
    k_pivot<<<NB, 256, 0, stream>>>(key, pivot, validCnt, candCount);
    k_compact<<<gA, 256, 0, stream>>>(key, pivot, candCount, candKey, candIdx);
    k_rank<<<NB, 1024, 0, stream>>>(candKey, candIdx, candCount, topKey, topIdx);
    k_gather<<<(NB * KPRE + 255) / 256, 256, 0, stream>>>(topKey, topIdx, label, boxp, anchors,
                                                          topBox, topScore, topLabel);
    k_mask<<<NB, 1024, 0, stream>>>(topBox, topLabel, mask);
    k_nms<<<NB, 64, 0, stream>>>(mask, validCnt, keepList, keepCount);
    k_out<<<(NB * MAXDET + 255) / 256, 256, 0, stream>>>(keepList, keepCount, topBox, topScore,
                                                         topLabel, out);
}

// Round 2
// 309.818 us; speedup vs baseline: 1.6988x; 1.6988x over previous
//
#include <hip/hip_runtime.h>
#include <cstdint>
#include <cmath>

#define NB 16
#define AANCH 16320
#define NCLS 80
#define KPRE 1000
#define MAXDET 300
#define NWORDS 16         // ceil(1000/64)
#define CANDCAP 16384

// logit(0.05) = ln(0.05/0.95)
#define THR_LOGIT -2.9444389791664403f

// ---------------- K1: per-anchor max-logit/argmax -> sortable key ----------------
__global__ void k_score(const float* __restrict__ cls, uint32_t* __restrict__ key,
                        int* __restrict__ label) {
    int a = blockIdx.x * blockDim.x + threadIdx.x;
    int b = blockIdx.y;
    if (a >= AANCH) return;
    const float4* p4 = (const float4*)(cls + ((size_t)b * AANCH + a) * NCLS);
    float best = -1e30f; int bi = 0;
#pragma unroll
    for (int c4 = 0; c4 < NCLS / 4; ++c4) {
        float4 v = p4[c4];
        if (v.x > best) { best = v.x; bi = c4 * 4 + 0; }
        if (v.y > best) { best = v.y; bi = c4 * 4 + 1; }
        if (v.z > best) { best = v.z; bi = c4 * 4 + 2; }
        if (v.w > best) { best = v.w; bi = c4 * 4 + 3; }
    }
    uint32_t k = 0;
    if (best > THR_LOGIT) {
        uint32_t ub = __float_as_uint(best);
        k = (ub & 0x80000000u) ? ~ub : (ub | 0x80000000u);  // order-preserving map
    }
    key[(size_t)b * AANCH + a] = k;
    label[(size_t)b * AANCH + a] = bi;
}

// ------------- K2: per-image pivot (13-bit histogram) + in-block compaction -------------
__global__ void k_pivot(const uint32_t* __restrict__ key, uint32_t* __restrict__ validCount,
                        uint32_t* __restrict__ candCount, uint32_t* __restrict__ candKey,
                        uint32_t* __restrict__ candIdx) {
    __shared__ uint32_t hist[8192];
    __shared__ uint32_t part[256];
    __shared__ uint32_t s_pivot, s_pos;
    int b = blockIdx.x, tid = threadIdx.x;
    for (int i = tid; i < 8192; i += 256) hist[i] = 0;
    __syncthreads();
    const uint32_t* kb = key + (size_t)b * AANCH;
    for (int i = tid; i < AANCH; i += 256) atomicAdd(&hist[kb[i] >> 19], 1u);
    __syncthreads();
    uint32_t s = 0;
    for (int i = 0; i < 32; ++i) s += hist[tid * 32 + i];
    part[tid] = s;
    __syncthreads();
    if (tid == 0) {
        uint32_t acc = 0; int tc = 0;
        for (int t = 255; t >= 0; --t) {
            if (acc + part[t] >= (uint32_t)KPRE) { tc = t; break; }
            acc += part[t];
        }
        uint32_t p1 = 0;
        for (int bin = tc * 32 + 31; bin >= tc * 32; --bin) {
            if (acc + hist[bin] >= (uint32_t)KPRE) { p1 = (uint32_t)bin; break; }
            acc += hist[bin];
        }
        s_pivot = p1;
        uint32_t nvalid = (uint32_t)AANCH - hist[0];   // bin 0 holds exactly key==0 entries
        validCount[b] = nvalid < (uint32_t)KPRE ? nvalid : (uint32_t)KPRE;
        s_pos = 0;
    }
    __syncthreads();
    uint32_t piv = s_pivot;
    for (int i = tid; i < AANCH; i += 256) {
        uint32_t k = kb[i];
        if ((k >> 19) >= piv) {
            uint32_t pos = atomicAdd(&s_pos, 1u);
            candKey[(size_t)b * CANDCAP + pos] = k;
            candIdx[(size_t)b * CANDCAP + pos] = (uint32_t)i;
        }
    }
    __syncthreads();
    if (tid == 0) candCount[b] = s_pos;
}

// ---------------- K3: exact rank of candidates (key desc, idx asc) ----------------
__global__ __launch_bounds__(256) void k_rank(const uint32_t* __restrict__ candKey,
                                              const uint32_t* __restrict__ candIdx,
                                              const uint32_t* __restrict__ candCount,
                                              uint32_t* __restrict__ topKey,
                                              uint32_t* __restrict__ topIdx) {
    __shared__ uint32_t tk[2048];
    __shared__ uint32_t ti[2048];
    int b = blockIdx.y, tid = threadIdx.x;
    int C = (int)candCount[b];
    if (blockIdx.x * 256 >= C) return;   // whole-block early exit
    const uint32_t* ck = candKey + (size_t)b * CANDCAP;
    const uint32_t* ci = candIdx + (size_t)b * CANDCAP;
    int c = blockIdx.x * 256 + tid;
    bool h = c < C;
    uint32_t mk = 0, mi = 0;
    if (h) { mk = ck[c]; mi = ci[c]; }
    uint32_t r = 0;
    for (int t0 = 0; t0 < C; t0 += 2048) {
        int n = C - t0; if (n > 2048) n = 2048;
        __syncthreads();
        for (int j = tid; j < n; j += 256) { tk[j] = ck[t0 + j]; ti[j] = ci[t0 + j]; }
        __syncthreads();
        for (int j = 0; j < n; ++j) {
            uint32_t kj = tk[j], ij = ti[j];
            r += (kj > mk) || (kj == mk && ij < mi);
        }
    }
    if (h && r < (uint32_t)KPRE) { topKey[b * KPRE + r] = mk; topIdx[b * KPRE + r] = mi; }
}

// ---------------- K4: gather + decode top-1000 ----------------
__global__ void k_gather(const uint32_t* __restrict__ topKey, const uint32_t* __restrict__ topIdx,
                         const int* __restrict__ label, const float* __restrict__ boxp,
                         const float* __restrict__ anchors, float4* __restrict__ topBox,
                         float* __restrict__ topScore, int* __restrict__ topLabel) {
    int t = blockIdx.x * blockDim.x + threadIdx.x;
    if (t >= NB * KPRE) return;
    int b = t / KPRE;
    uint32_t key = topKey[t];
    uint32_t idx = topIdx[t];
    const float* an = anchors + (size_t)idx * 4;
    float a0 = an[0], a1 = an[1], a2 = an[2], a3 = an[3];
    const float* dp = boxp + ((size_t)b * AANCH + idx) * 4;
    float d0 = dp[0], d1 = dp[1], d2 = dp[2], d3 = dp[3];
    float aw = a2 - a0, ah = a3 - a1;
    float acx = a0 + 0.5f * aw, acy = a1 + 0.5f * ah;
    float cx = d0 * aw + acx, cy = d1 * ah + acy;
    float w = expf(d2) * aw, h = expf(d3) * ah;
    float x1 = cx - 0.5f * w, y1 = cy - 0.5f * h;
    float x2 = cx + 0.5f * w, y2 = cy + 0.5f * h;
    x1 = fminf(fmaxf(x1, 0.0f), 512.0f);
    y1 = fminf(fmaxf(y1, 0.0f), 512.0f);
    x2 = fminf(fmaxf(x2, 0.0f), 512.0f);
    y2 = fminf(fmaxf(y2, 0.0f), 512.0f);
    float score;
    if (key == 0u) {
        score = -1.0f;
    } else {
        uint32_t ub = (key & 0x80000000u) ? (key ^ 0x80000000u) : ~key;
        float lg = __uint_as_float(ub);
        score = 1.0f / (1.0f + expf(-lg));
    }
    topBox[t] = make_float4(x1, y1, x2, y2);
    topScore[t] = score;
    topLabel[t] = label[(size_t)b * AANCH + idx];
}

// ---------------- K5: suppression bitmask, 64x64 tiles (upper triangle only) ----------------
// layout: mask[(b*NWORDS + colBlk)*KPRE + i]  (coalesced writes over i)
__global__ __launch_bounds__(64) void k_mask(const float4* __restrict__ topBox,
                                             const int* __restrict__ topLabel,
                                             unsigned long long* __restrict__ mask) {
    int b = blockIdx.y;
    int rb = blockIdx.x >> 4;
    int cb = blockIdx.x & 15;
    if (cb < rb) return;   // lower-triangle words are masked off at consume time
    __shared__ float4 cob[64];
    __shared__ float car[64];
    int lane = threadIdx.x;
    int j = cb * 64 + lane;
    float4 vj;
    if (j < KPRE) {
        vj = topBox[b * KPRE + j];
        float off = (float)topLabel[b * KPRE + j] * 10000.0f;
        vj.x += off; vj.y += off; vj.z += off; vj.w += off;
    } else {
        vj = make_float4(-1e30f, -1e30f, -1e30f, -1e30f);
    }
    cob[lane] = vj;
    car[lane] = fmaxf(vj.z - vj.x, 0.0f) * fmaxf(vj.w - vj.y, 0.0f);
    __syncthreads();
    int i = rb * 64 + lane;
    if (i >= KPRE) return;
    float4 bi = topBox[b * KPRE + i];
    float offi = (float)topLabel[b * KPRE + i] * 10000.0f;
    bi.x += offi; bi.y += offi; bi.z += offi; bi.w += offi;
    float ai = fmaxf(bi.z - bi.x, 0.0f) * fmaxf(bi.w - bi.y, 0.0f);
    unsigned long long bits = 0;
    int jbase = cb * 64;
#pragma unroll 4
    for (int jj = 0; jj < 64; ++jj) {
        int jg = jbase + jj;
        if (jg <= i || jg >= KPRE) continue;
        float4 bj = cob[jj];
        float ltx = fmaxf(bi.x, bj.x), lty = fmaxf(bi.y, bj.y);
        float rbx = fminf(bi.z, bj.z), rby = fminf(bi.w, bj.w);
        float wx = fmaxf(rbx - ltx, 0.0f), wy = fmaxf(rby - lty, 0.0f);
        float inter = wx * wy;
        float iou = inter / fmaxf(ai + car[jj] - inter, 1e-6f);
        if (iou > 0.5f) bits |= 1ull << jj;
    }
    mask[((size_t)b * NWORDS + cb) * KPRE + i] = bits;
}

// ---------------- K6: per-image serial NMS sweep (1 wave/image) + output write ----------------
__device__ inline unsigned long long shfl_u64(unsigned long long v, int lane) {
    int lo = __shfl((int)(v & 0xffffffffull), lane, 64);
    int hi = __shfl((int)(v >> 32), lane, 64);
    return ((unsigned long long)(unsigned int)hi << 32) | (unsigned int)lo;
}

__global__ void k_nmsout(const unsigned long long* __restrict__ mask,
                         const uint32_t* __restrict__ validCount,
                         const float4* __restrict__ topBox, const float* __restrict__ topScore,
                         const int* __restrict__ topLabel, float* __restrict__ out) {
    __shared__ int kl[MAXDET];
    int b = blockIdx.x, lane = threadIdx.x;  // 64 threads = 1 wave
    int V = (int)validCount[b];
    const unsigned long long* mb = mask + (size_t)b * NWORDS * KPRE;
    unsigned long long remv = 0;
    int count = 0;
    int base = lane * 64;
#define LDROW(I) ((lane < NWORDS && (I) < KPRE) ? mb[(size_t)lane * KPRE + (I)] : 0ull)
    unsigned long long r0 = LDROW(0), r1 = LDROW(1), r2 = LDROW(2), r3 = LDROW(3);
    for (int i = 0; i < V; ++i) {
        unsigned long long row = r0; r0 = r1; r1 = r2; r2 = r3; r3 = LDROW(i + 4);
        // zero bits with j <= i (covers unwritten lower-triangle words too)
        if (base + 63 <= i) row = 0ull;
        else if (base <= i) row &= (~0ull) << (i - base + 1);
        unsigned long long w = shfl_u64(remv, i >> 6);
        bool sup = (w >> (i & 63)) & 1ull;
        if (!sup) {
            if (lane == 0 && count < MAXDET) kl[count] = i;
            ++count;                       // uniform across lanes
            remv |= row;
            if (count >= MAXDET) break;
        }
    }
#undef LDROW
    __syncthreads();
    for (int k = lane; k < MAXDET; k += 64) {
        float4 box = make_float4(0.f, 0.f, 0.f, 0.f);
        float sc = 0.0f, lb = 0.0f;
        if (k < count) {
            int i = kl[k];
            box = topBox[b * KPRE + i];
            sc = topScore[b * KPRE + i];
            lb = (float)(topLabel[b * KPRE + i] + 1);
        }
        int t = b * MAXDET + k;
        float* ob = out + (size_t)t * 4;
        ob[0] = box.x; ob[1] = box.y; ob[2] = box.z; ob[3] = box.w;
        out[(size_t)NB * MAXDET * 4 + t] = sc;
        out[(size_t)NB * MAXDET * 4 + (size_t)NB * MAXDET + t] = lb;
    }
}

extern "C" void kernel_launch(void* const* d_in, const int* in_sizes, int n_in,
                              void* d_out, int out_size, void* d_ws, size_t ws_size,
                              hipStream_t stream) {
    const float* cls = (const float*)d_in[0];
    const float* boxp = (const float*)d_in[1];
    const float* anchors = (const float*)d_in[2];
    float* out = (float*)d_out;

    char* wsp = (char*)d_ws;
    size_t off = 0;
    auto carve = [&](size_t bytes) -> void* {
        void* p = wsp + off;
        off += (bytes + 255) & ~(size_t)255;
        return p;
    };
    unsigned long long* mask = (unsigned long long*)carve((size_t)NB * KPRE * NWORDS * 8 + 1024);
    uint32_t* key       = (uint32_t*)carve((size_t)NB * AANCH * 4);
    int*      label     = (int*)carve((size_t)NB * AANCH * 4);
    uint32_t* candKey   = (uint32_t*)carve((size_t)NB * CANDCAP * 4);
    uint32_t* candIdx   = (uint32_t*)carve((size_t)NB * CANDCAP * 4);
    float4*   topBox    = (float4*)carve((size_t)NB * KPRE * 16);
    uint32_t* topKey    = (uint32_t*)carve((size_t)NB * KPRE * 4);
    uint32_t* topIdx    = (uint32_t*)carve((size_t)NB * KPRE * 4);
    float*    topScore  = (float*)carve((size_t)NB * KPRE * 4);
    int*      topLabel  = (int*)carve((size_t)NB * KPRE * 4);
    uint32_t* validCnt  = (uint32_t*)carve((size_t)NB * 4);
    uint32_t* candCount = (uint32_t*)carve((size_t)NB * 4);
    (void)ws_size; (void)out_size; (void)n_in; (void)in_sizes;

    dim3 gA((AANCH + 255) / 256, NB);
    k_score<<<gA, 256, 0, stream>>>(cls, key, label);
    k_pivot<<<NB, 256, 0, stream>>>(key, validCnt, candCount, candKey, candIdx);
    k_rank<<<dim3(CANDCAP / 256, NB), 256, 0, stream>>>(candKey, candIdx, candCount, topKey, topIdx);
    k_gather<<<(NB * KPRE + 255) / 256, 256, 0, stream>>>(topKey, topIdx, label, boxp, anchors,
                                                          topBox, topScore, topLabel);
    k_mask<<<dim3(256, NB), 64, 0, stream>>>(topBox, topLabel, mask);
    k_nmsout<<<NB, 64, 0, stream>>>(mask, validCnt, topBox, topScore, topLabel, out);
}

// Round 3
// 295.458 us; speedup vs baseline: 1.7814x; 1.0486x over previous
//
#include <hip/hip_runtime.h>
#include <cstdint>
#include <cmath>

#define NB 16
#define AANCH 16320
#define NCLS 80
#define KPRE 1000
#define MAXDET 300
#define NCH 16            // 16 chunks of 64 >= 1000 candidates
#define CANDCAP 16384
#define HBINS 8192

// logit(0.05)
#define THR_LOGIT -2.9444389791664403f

// ---------------- K0: zero hist + candCount ----------------
__global__ void k_zero(uint32_t* __restrict__ hist, uint32_t* __restrict__ candCount) {
    int t = blockIdx.x * blockDim.x + threadIdx.x;
    if (t < NB * HBINS) hist[t] = 0;
    if (t < NB) candCount[t] = 0;
}

// ---------------- K1: coalesced LDS-staged max/argmax + fused histogram ----------------
__global__ __launch_bounds__(256) void k_score(const float* __restrict__ cls,
                                               uint32_t* __restrict__ key,
                                               int* __restrict__ label,
                                               uint32_t* __restrict__ hist) {
    __shared__ float tile[64 * 85];   // 64 anchors x 80 classes, stride 85 (gcd(85,32)=1)
    int b = blockIdx.y;
    int a0 = blockIdx.x * 64;
    int t = threadIdx.x;
    const float4* src = (const float4*)(cls + ((size_t)b * AANCH + a0) * NCLS);
#pragma unroll
    for (int it = 0; it < 5; ++it) {          // 1280 float4, fully coalesced
        int f4 = it * 256 + t;
        float4 v = src[f4];
        int r = f4 / 20, c4 = f4 % 20;
        float* dst = &tile[r * 85 + c4 * 4];
        dst[0] = v.x; dst[1] = v.y; dst[2] = v.z; dst[3] = v.w;
    }
    __syncthreads();
    int a = t >> 2, g = t & 3;                // 4 lanes per anchor
    const float* row = &tile[a * 85 + g * 20];
    float best = row[0]; int bi = g * 20;
#pragma unroll
    for (int i = 1; i < 20; ++i) {
        float v = row[i];
        if (v > best) { best = v; bi = g * 20 + i; }
    }
#pragma unroll
    for (int m = 1; m <= 2; m <<= 1) {        // reduce the 4-lane group (first-max wins)
        float ob = __shfl_xor(best, m, 64);
        int oi = __shfl_xor(bi, m, 64);
        if (ob > best || (ob == best && oi < bi)) { best = ob; bi = oi; }
    }
    if (g == 0) {
        uint32_t k = 0;
        if (best > THR_LOGIT) {
            uint32_t ub = __float_as_uint(best);
            k = (ub & 0x80000000u) ? ~ub : (ub | 0x80000000u);  // order-preserving map
        }
        int ag = a0 + a;
        key[(size_t)b * AANCH + ag] = k;
        label[(size_t)b * AANCH + ag] = bi;
        atomicAdd(&hist[b * HBINS + (k >> 19)], 1u);
    }
}

// ---------------- K2: pivot selection from histogram ----------------
__global__ __launch_bounds__(256) void k_select(const uint32_t* __restrict__ hist,
                                                uint32_t* __restrict__ pivot,
                                                uint32_t* __restrict__ validCount) {
    __shared__ uint32_t h[HBINS];
    __shared__ uint32_t part[256];
    int b = blockIdx.x, tid = threadIdx.x;
    const uint32_t* hb = hist + b * HBINS;
    for (int i = tid; i < HBINS; i += 256) h[i] = hb[i];
    __syncthreads();
    uint32_t s = 0;
#pragma unroll
    for (int i = 0; i < 32; ++i) s += h[tid * 32 + ((i + tid) & 31)];  // rotated: no bank conflict
    part[tid] = s;
    __syncthreads();
    if (tid == 0) {
        uint32_t acc = 0; int tc = 0;
        for (int t2 = 255; t2 >= 0; --t2) {
            if (acc + part[t2] >= (uint32_t)KPRE) { tc = t2; break; }
            acc += part[t2];
        }
        uint32_t p1 = 0;
        for (int bin = tc * 32 + 31; bin >= tc * 32; --bin) {
            if (acc + h[bin] >= (uint32_t)KPRE) { p1 = (uint32_t)bin; break; }
            acc += h[bin];
        }
        pivot[b] = p1;
        uint32_t nvalid = (uint32_t)AANCH - h[0];   // bin 0 holds exactly key==0 entries
        validCount[b] = nvalid < (uint32_t)KPRE ? nvalid : (uint32_t)KPRE;
    }
}

// ---------------- K3: compact candidates (block-aggregated atomics) ----------------
__global__ void k_compact(const uint32_t* __restrict__ key, const uint32_t* __restrict__ pivot,
                          uint32_t* __restrict__ candCount, uint32_t* __restrict__ candKey,
                          uint32_t* __restrict__ candIdx) {
    __shared__ uint32_t lcnt, lbase;
    int a = blockIdx.x * blockDim.x + threadIdx.x;
    int b = blockIdx.y;
    if (threadIdx.x == 0) lcnt = 0;
    __syncthreads();
    uint32_t k = 0, lpos = 0;
    bool pass = false;
    if (a < AANCH) {
        k = key[(size_t)b * AANCH + a];
        pass = (k >> 19) >= pivot[b];
        if (pass) lpos = atomicAdd(&lcnt, 1u);
    }
    __syncthreads();
    if (threadIdx.x == 0) lbase = atomicAdd(&candCount[b], lcnt);
    __syncthreads();
    if (pass) {
        uint32_t pos = lbase + lpos;
        candKey[(size_t)b * CANDCAP + pos] = k;
        candIdx[(size_t)b * CANDCAP + pos] = (uint32_t)a;
    }
}

// ---------------- K4: exact rank (key desc, idx asc) ----------------
__global__ __launch_bounds__(256) void k_rank(const uint32_t* __restrict__ candKey,
                                              const uint32_t* __restrict__ candIdx,
                                              const uint32_t* __restrict__ candCount,
                                              uint32_t* __restrict__ topKey,
                                              uint32_t* __restrict__ topIdx) {
    __shared__ uint32_t tk[2048];
    __shared__ uint32_t ti[2048];
    int b = blockIdx.y, tid = threadIdx.x;
    int C = (int)candCount[b];
    if (blockIdx.x * 256 >= C) return;
    const uint32_t* ck = candKey + (size_t)b * CANDCAP;
    const uint32_t* ci = candIdx + (size_t)b * CANDCAP;
    int c = blockIdx.x * 256 + tid;
    bool h = c < C;
    uint32_t mk = 0, mi = 0;
    if (h) { mk = ck[c]; mi = ci[c]; }
    uint32_t r = 0;
    for (int t0 = 0; t0 < C; t0 += 2048) {
        int n = C - t0; if (n > 2048) n = 2048;
        __syncthreads();
        for (int j = tid; j < n; j += 256) { tk[j] = ck[t0 + j]; ti[j] = ci[t0 + j]; }
        __syncthreads();
        for (int j = 0; j < n; ++j) {
            uint32_t kj = tk[j], ij = ti[j];
            r += (kj > mk) || (kj == mk && ij < mi);
        }
    }
    if (h && r < (uint32_t)KPRE) { topKey[b * KPRE + r] = mk; topIdx[b * KPRE + r] = mi; }
}

// ---------------- K5: gather + decode top-1000 ----------------
__global__ void k_gather(const uint32_t* __restrict__ topKey, const uint32_t* __restrict__ topIdx,
                         const int* __restrict__ label, const float* __restrict__ boxp,
                         const float* __restrict__ anchors, float4* __restrict__ topBox,
                         float* __restrict__ topScore, int* __restrict__ topLabel) {
    int t = blockIdx.x * blockDim.x + threadIdx.x;
    if (t >= NB * KPRE) return;
    int b = t / KPRE;
    uint32_t key = topKey[t];
    uint32_t idx = topIdx[t];
    const float* an = anchors + (size_t)idx * 4;
    float a0 = an[0], a1 = an[1], a2 = an[2], a3 = an[3];
    const float* dp = boxp + ((size_t)b * AANCH + idx) * 4;
    float d0 = dp[0], d1 = dp[1], d2 = dp[2], d3 = dp[3];
    float aw = a2 - a0, ah = a3 - a1;
    float acx = a0 + 0.5f * aw, acy = a1 + 0.5f * ah;
    float cx = d0 * aw + acx, cy = d1 * ah + acy;
    float w = expf(d2) * aw, h = expf(d3) * ah;
    float x1 = fminf(fmaxf(cx - 0.5f * w, 0.0f), 512.0f);
    float y1 = fminf(fmaxf(cy - 0.5f * h, 0.0f), 512.0f);
    float x2 = fminf(fmaxf(cx + 0.5f * w, 0.0f), 512.0f);
    float y2 = fminf(fmaxf(cy + 0.5f * h, 0.0f), 512.0f);
    float score;
    if (key == 0u) {
        score = -1.0f;
    } else {
        uint32_t ub = (key & 0x80000000u) ? (key ^ 0x80000000u) : ~key;
        score = 1.0f / (1.0f + expf(-__uint_as_float(ub)));
    }
    topBox[t] = make_float4(x1, y1, x2, y2);
    topScore[t] = score;
    topLabel[t] = label[(size_t)b * AANCH + idx];
}

// ---------------- K6: TRANSPOSED suppression mask via ballot ----------------
// MT[((b*NCH + srcChunk)*NCH + tgtChunk)*64 + j] : bit i = "cand srcChunk*64+i suppresses cand tgtChunk*64+j"
__global__ __launch_bounds__(64) void k_maskT(const float4* __restrict__ topBox,
                                              const int* __restrict__ topLabel,
                                              unsigned long long* __restrict__ maskT) {
    int b = blockIdx.y;
    int tt = blockIdx.x;                 // 0..135 triangular -> (rb<=cb)
    int rb = 0;
    while (tt >= NCH - rb) { tt -= NCH - rb; ++rb; }
    int cb = rb + tt;
    __shared__ float4 cob[64];
    __shared__ float car[64];
    int lane = threadIdx.x;
    int j = cb * 64 + lane;
    float4 vj;
    if (j < KPRE) {
        vj = topBox[b * KPRE + j];
        float off = (float)topLabel[b * KPRE + j] * 10000.0f;
        vj.x += off; vj.y += off; vj.z += off; vj.w += off;
    } else {
        vj = make_float4(-3e37f, -3e37f, -3e37f, -3e37f);
    }
    cob[lane] = vj;
    car[lane] = fmaxf(vj.z - vj.x, 0.0f) * fmaxf(vj.w - vj.y, 0.0f);
    int i = rb * 64 + lane;
    float4 bi;
    if (i < KPRE) {
        bi = topBox[b * KPRE + i];
        float off = (float)topLabel[b * KPRE + i] * 10000.0f;
        bi.x += off; bi.y += off; bi.z += off; bi.w += off;
    } else {
        bi = make_float4(-3e37f, -3e37f, -3e37f, -3e37f);
    }
    float ai = fmaxf(bi.z - bi.x, 0.0f) * fmaxf(bi.w - bi.y, 0.0f);
    __syncthreads();
    unsigned long long myword = 0;
#pragma unroll 8
    for (int jj = 0; jj < 64; ++jj) {
        int jg = cb * 64 + jj;
        float4 bj = cob[jj];
        float ltx = fmaxf(bi.x, bj.x), lty = fmaxf(bi.y, bj.y);
        float rbx = fminf(bi.z, bj.z), rby = fminf(bi.w, bj.w);
        float wx = fmaxf(rbx - ltx, 0.0f), wy = fmaxf(rby - lty, 0.0f);
        float inter = wx * wy;
        float iou = inter / fmaxf(ai + car[jj] - inter, 1e-6f);
        bool pred = (iou > 0.5f) && (i < jg) && (i < KPRE) && (jg < KPRE);
        unsigned long long bal = __ballot(pred);     // bit <lane> = source i suppresses target jg
        if (lane == jj) myword = bal;
    }
    maskT[(((size_t)b * NCH + rb) * NCH + cb) * 64 + lane] = myword;
}

// ---------------- K7: ballot-based greedy NMS + output (1 wave/image) ----------------
__global__ __launch_bounds__(64) void k_nmsout(const unsigned long long* __restrict__ maskT,
                                               const uint32_t* __restrict__ validCount,
                                               const float4* __restrict__ topBox,
                                               const float* __restrict__ topScore,
                                               const int* __restrict__ topLabel,
                                               float* __restrict__ out) {
    __shared__ unsigned long long km[NCH];   // kept mask per chunk (uniform)
    __shared__ int pf[NCH + 1];
    int b = blockIdx.x, lane = threadIdx.x;
    int V = (int)validCount[b];
    if (lane < NCH) km[lane] = 0ull;
    __syncthreads();
    const unsigned long long* mtb = maskT + (size_t)b * NCH * NCH * 64;
    int count = 0;
    unsigned long long mt[NCH];
#pragma unroll
    for (int s = 0; s < NCH; ++s) mt[s] = mtb[((size_t)s * NCH + 0) * 64 + lane];
    for (int c = 0; c < NCH; ++c) {
        if (c * 64 >= V || count >= MAXDET) break;
        unsigned long long cur[NCH];
#pragma unroll
        for (int s = 0; s < NCH; ++s) cur[s] = mt[s];
        if (c + 1 < NCH) {
#pragma unroll
            for (int s = 0; s < NCH; ++s) mt[s] = mtb[((size_t)s * NCH + (c + 1)) * 64 + lane];
        }
        // dead from kept candidates of earlier chunks (km[s]==0 for s>=c)
        unsigned long long dd = 0;
        unsigned long long colbits = 0;
#pragma unroll
        for (int s = 0; s < NCH; ++s) {
            if (s == c) colbits = cur[s];
            dd |= (cur[s] & km[s]);
        }
        bool dead = dd != 0ull;
        bool valid = (c * 64 + lane) < V;
        bool kept = false;
        unsigned long long kmask = 0;
        while (count < MAXDET) {
            unsigned long long undec = __ballot((!dead) && (!kept) && valid);
            if (undec == 0ull) break;
            int f = __builtin_ctzll(undec);     // lowest index = next greedy keep
            kmask |= 1ull << f;
            ++count;
            if (lane == f) kept = true;
            dead = dead || (((colbits >> f) & 1ull) != 0ull);
        }
        if (lane == 0) km[c] = kmask;
        __syncthreads();
    }
    __syncthreads();
    if (lane == 0) {
        int acc = 0;
        for (int cc = 0; cc < NCH; ++cc) { pf[cc] = acc; acc += __popcll(km[cc]); }
        pf[NCH] = acc;
    }
    __syncthreads();
    int total = pf[NCH];
    // emit kept detections
    for (int cc = 0; cc < NCH; ++cc) {
        unsigned long long m = km[cc];
        if ((m >> lane) & 1ull) {
            int slot = pf[cc] + __popcll(m & ((1ull << lane) - 1ull));
            int g = cc * 64 + lane;
            int tdx = b * MAXDET + slot;
            float4 box = topBox[b * KPRE + g];
            out[(size_t)tdx * 4 + 0] = box.x;
            out[(size_t)tdx * 4 + 1] = box.y;
            out[(size_t)tdx * 4 + 2] = box.z;
            out[(size_t)tdx * 4 + 3] = box.w;
            out[(size_t)NB * MAXDET * 4 + tdx] = topScore[b * KPRE + g];
            out[(size_t)NB * MAXDET * 5 + tdx] = (float)(topLabel[b * KPRE + g] + 1);
        }
    }
    // zero-fill the tail
    for (int k = lane; k < MAXDET; k += 64) {
        if (k >= total) {
            int tdx = b * MAXDET + k;
            out[(size_t)tdx * 4 + 0] = 0.0f;
            out[(size_t)tdx * 4 + 1] = 0.0f;
            out[(size_t)tdx * 4 + 2] = 0.0f;
            out[(size_t)tdx * 4 + 3] = 0.0f;
            out[(size_t)NB * MAXDET * 4 + tdx] = 0.0f;
            out[(size_t)NB * MAXDET * 5 + tdx] = 0.0f;
        }
    }
}

extern "C" void kernel_launch(void* const* d_in, const int* in_sizes, int n_in,
                              void* d_out, int out_size, void* d_ws, size_t ws_size,
                              hipStream_t stream) {
    const float* cls = (const float*)d_in[0];
    const float* boxp = (const float*)d_in[1];
    const float* anchors = (const float*)d_in[2];
    float* out = (float*)d_out;

    char* wsp = (char*)d_ws;
    size_t off = 0;
    auto carve = [&](size_t bytes) -> void* {
        void* p = wsp + off;
        off += (bytes + 255) & ~(size_t)255;
        return p;
    };
    unsigned long long* maskT = (unsigned long long*)carve((size_t)NB * NCH * NCH * 64 * 8);
    uint32_t* hist      = (uint32_t*)carve((size_t)NB * HBINS * 4);
    uint32_t* key       = (uint32_t*)carve((size_t)NB * AANCH * 4);
    int*      label     = (int*)carve((size_t)NB * AANCH * 4);
    uint32_t* candKey   = (uint32_t*)carve((size_t)NB * CANDCAP * 4);
    uint32_t* candIdx   = (uint32_t*)carve((size_t)NB * CANDCAP * 4);
    float4*   topBox    = (float4*)carve((size_t)NB * KPRE * 16);
    uint32_t* topKey    = (uint32_t*)carve((size_t)NB * KPRE * 4);
    uint32_t* topIdx    = (uint32_t*)carve((size_t)NB * KPRE * 4);
    float*    topScore  = (float*)carve((size_t)NB * KPRE * 4);
    int*      topLabel  = (int*)carve((size_t)NB * KPRE * 4);
    uint32_t* pivot     = (uint32_t*)carve((size_t)NB * 4);
    uint32_t* validCnt  = (uint32_t*)carve((size_t)NB * 4);
    uint32_t* candCount = (uint32_t*)carve((size_t)NB * 4);
    (void)ws_size; (void)out_size; (void)n_in; (void)in_sizes;

    k_zero<<<(NB * HBINS + 1023) / 1024, 1024, 0, stream>>>(hist, candCount);
    k_score<<<dim3(AANCH / 64, NB), 256, 0, stream>>>(cls, key, label, hist);
    k_select<<<NB, 256, 0, stream>>>(hist, pivot, validCnt);
    k_compact<<<dim3((AANCH + 255) / 256, NB), 256, 0, stream>>>(key, pivot, candCount,
                                                                 candKey, candIdx);
    k_rank<<<dim3(CANDCAP / 256, NB), 256, 0, stream>>>(candKey, candIdx, candCount,
                                                        topKey, topIdx);
    k_gather<<<(NB * KPRE + 255) / 256, 256, 0, stream>>>(topKey, topIdx, label, boxp, anchors,
                                                          topBox, topScore, topLabel);
    k_maskT<<<dim3(136, NB), 64, 0, stream>>>(topBox, topLabel, maskT);
    k_nmsout<<<NB, 64, 0, stream>>>(maskT, validCnt, topBox, topScore, topLabel, out);
}

// Round 4
// 238.159 us; speedup vs baseline: 2.2100x; 1.2406x over previous
//
#include <hip/hip_runtime.h>
#include <cstdint>
#include <cmath>

#define NB 16
#define AANCH 16320
#define NCLS 80
#define KPRE 1000
#define MAXDET 300
#define NCH 16            // 16 chunks of 64 >= 1000 candidates
#define CANDCAP 16384
#define HBINS 8192

// logit(0.05)
#define THR_LOGIT -2.9444389791664403f

// ---------------- K1: streaming max/argmax, 4 lanes per anchor, no LDS ----------------
__global__ __launch_bounds__(256) void k_score(const float* __restrict__ cls,
                                               uint32_t* __restrict__ key,
                                               int* __restrict__ label) {
    int b = blockIdx.y;
    int a0 = blockIdx.x * 64;
    int t = threadIdx.x;
    int al = t >> 2, g = t & 3;               // 4 lanes per anchor
    const float4* p = (const float4*)(cls + ((size_t)b * AANCH + a0) * NCLS) + al * 20 + g;
    float best = -3e38f; int bi = 0;
#pragma unroll
    for (int i = 0; i < 5; ++i) {             // classes c = 4g + 16i + e (ascending per thread)
        float4 v = p[4 * i];
        int c0 = 4 * g + 16 * i;
        if (v.x > best) { best = v.x; bi = c0 + 0; }
        if (v.y > best) { best = v.y; bi = c0 + 1; }
        if (v.z > best) { best = v.z; bi = c0 + 2; }
        if (v.w > best) { best = v.w; bi = c0 + 3; }
    }
#pragma unroll
    for (int m = 1; m <= 2; m <<= 1) {        // reduce 4-lane group, first-max (lowest class) wins
        float ob = __shfl_xor(best, m, 64);
        int oi = __shfl_xor(bi, m, 64);
        if (ob > best || (ob == best && oi < bi)) { best = ob; bi = oi; }
    }
    if (g == 0) {
        uint32_t k = 0;
        if (best > THR_LOGIT) {
            uint32_t ub = __float_as_uint(best);
            k = (ub & 0x80000000u) ? ~ub : (ub | 0x80000000u);  // order-preserving map
        }
        int ag = a0 + al;
        key[(size_t)b * AANCH + ag] = k;
        label[(size_t)b * AANCH + ag] = bi;
    }
}

// ------- K2: fused per-image hist + pivot + compaction (keys staged in LDS) -------
__global__ __launch_bounds__(1024) void k_fsel(const uint32_t* __restrict__ key,
                                               uint32_t* __restrict__ validCount,
                                               uint32_t* __restrict__ candCount,
                                               uint32_t* __restrict__ candKey,
                                               uint32_t* __restrict__ candIdx) {
    __shared__ uint32_t kk[AANCH];     // 65280 B
    __shared__ uint32_t hist[HBINS];   // 32768 B
    __shared__ uint32_t part[256];
    __shared__ uint32_t s_pivot, s_pos;
    int b = blockIdx.x, tid = threadIdx.x;
    for (int i = tid; i < HBINS; i += 1024) hist[i] = 0;
    if (tid == 0) s_pos = 0;
    __syncthreads();
    const uint32_t* kb = key + (size_t)b * AANCH;
    for (int i = tid; i < AANCH; i += 1024) {
        uint32_t k = kb[i];
        kk[i] = k;
        atomicAdd(&hist[k >> 19], 1u);
    }
    __syncthreads();
    if (tid < 256) {
        uint32_t s = 0;
#pragma unroll
        for (int i = 0; i < 32; ++i) s += hist[tid * 32 + ((i + tid) & 31)];  // 2-way only
        part[tid] = s;
    }
    __syncthreads();
    if (tid == 0) {
        uint32_t acc = 0; int tc = 0;
        for (int t2 = 255; t2 >= 0; --t2) {
            if (acc + part[t2] >= (uint32_t)KPRE) { tc = t2; break; }
            acc += part[t2];
        }
        uint32_t p1 = 0;
        for (int bin = tc * 32 + 31; bin >= tc * 32; --bin) {
            if (acc + hist[bin] >= (uint32_t)KPRE) { p1 = (uint32_t)bin; break; }
            acc += hist[bin];
        }
        s_pivot = p1;
        uint32_t nvalid = (uint32_t)AANCH - hist[0];   // bin 0 holds exactly key==0 entries
        validCount[b] = nvalid < (uint32_t)KPRE ? nvalid : (uint32_t)KPRE;
    }
    __syncthreads();
    uint32_t piv = s_pivot;
    for (int i = tid; i < AANCH; i += 1024) {
        uint32_t k = kk[i];
        if ((k >> 19) >= piv) {
            uint32_t pos = atomicAdd(&s_pos, 1u);
            candKey[(size_t)b * CANDCAP + pos] = k;
            candIdx[(size_t)b * CANDCAP + pos] = (uint32_t)i;
        }
    }
    __syncthreads();
    if (tid == 0) candCount[b] = s_pos;
}

// ---------------- K3: exact rank (key desc, idx asc) ----------------
__global__ __launch_bounds__(256) void k_rank(const uint32_t* __restrict__ candKey,
                                              const uint32_t* __restrict__ candIdx,
                                              const uint32_t* __restrict__ candCount,
                                              uint32_t* __restrict__ topKey,
                                              uint32_t* __restrict__ topIdx) {
    __shared__ uint32_t tk[2048];
    __shared__ uint32_t ti[2048];
    int b = blockIdx.y, tid = threadIdx.x;
    int C = (int)candCount[b];
    if (blockIdx.x * 256 >= C) return;
    const uint32_t* ck = candKey + (size_t)b * CANDCAP;
    const uint32_t* ci = candIdx + (size_t)b * CANDCAP;
    int c = blockIdx.x * 256 + tid;
    bool h = c < C;
    uint32_t mk = 0, mi = 0;
    if (h) { mk = ck[c]; mi = ci[c]; }
    uint32_t r = 0;
    for (int t0 = 0; t0 < C; t0 += 2048) {
        int n = C - t0; if (n > 2048) n = 2048;
        __syncthreads();
        for (int j = tid; j < n; j += 256) { tk[j] = ck[t0 + j]; ti[j] = ci[t0 + j]; }
        __syncthreads();
        for (int j = 0; j < n; ++j) {
            uint32_t kj = tk[j], ij = ti[j];
            r += (kj > mk) || (kj == mk && ij < mi);
        }
    }
    if (h && r < (uint32_t)KPRE) { topKey[b * KPRE + r] = mk; topIdx[b * KPRE + r] = mi; }
}

// ---------------- K4: gather + decode top-1000 ----------------
__global__ void k_gather(const uint32_t* __restrict__ topKey, const uint32_t* __restrict__ topIdx,
                         const int* __restrict__ label, const float* __restrict__ boxp,
                         const float* __restrict__ anchors, float4* __restrict__ topBox,
                         float* __restrict__ topScore, int* __restrict__ topLabel) {
    int t = blockIdx.x * blockDim.x + threadIdx.x;
    if (t >= NB * KPRE) return;
    int b = t / KPRE;
    uint32_t key = topKey[t];
    uint32_t idx = topIdx[t];
    const float* an = anchors + (size_t)idx * 4;
    float a0 = an[0], a1 = an[1], a2 = an[2], a3 = an[3];
    const float* dp = boxp + ((size_t)b * AANCH + idx) * 4;
    float d0 = dp[0], d1 = dp[1], d2 = dp[2], d3 = dp[3];
    float aw = a2 - a0, ah = a3 - a1;
    float acx = a0 + 0.5f * aw, acy = a1 + 0.5f * ah;
    float cx = d0 * aw + acx, cy = d1 * ah + acy;
    float w = expf(d2) * aw, h = expf(d3) * ah;
    float x1 = fminf(fmaxf(cx - 0.5f * w, 0.0f), 512.0f);
    float y1 = fminf(fmaxf(cy - 0.5f * h, 0.0f), 512.0f);
    float x2 = fminf(fmaxf(cx + 0.5f * w, 0.0f), 512.0f);
    float y2 = fminf(fmaxf(cy + 0.5f * h, 0.0f), 512.0f);
    float score;
    if (key == 0u) {
        score = -1.0f;
    } else {
        uint32_t ub = (key & 0x80000000u) ? (key ^ 0x80000000u) : ~key;
        score = 1.0f / (1.0f + expf(-__uint_as_float(ub)));
    }
    topBox[t] = make_float4(x1, y1, x2, y2);
    topScore[t] = score;
    topLabel[t] = label[(size_t)b * AANCH + idx];
}

// ---------------- K5: TRANSPOSED suppression mask via ballot ----------------
// MT[((b*NCH + srcChunk)*NCH + tgtChunk)*64 + j] : bit i = "cand srcChunk*64+i suppresses cand tgtChunk*64+j"
__global__ __launch_bounds__(64) void k_maskT(const float4* __restrict__ topBox,
                                              const int* __restrict__ topLabel,
                                              unsigned long long* __restrict__ maskT) {
    int b = blockIdx.y;
    int tt = blockIdx.x;                 // 0..135 triangular -> (rb<=cb)
    int rb = 0;
    while (tt >= NCH - rb) { tt -= NCH - rb; ++rb; }
    int cb = rb + tt;
    __shared__ float4 cob[64];
    __shared__ float car[64];
    int lane = threadIdx.x;
    int j = cb * 64 + lane;
    float4 vj;
    if (j < KPRE) {
        vj = topBox[b * KPRE + j];
        float off = (float)topLabel[b * KPRE + j] * 10000.0f;
        vj.x += off; vj.y += off; vj.z += off; vj.w += off;
    } else {
        vj = make_float4(-3e37f, -3e37f, -3e37f, -3e37f);
    }
    cob[lane] = vj;
    car[lane] = fmaxf(vj.z - vj.x, 0.0f) * fmaxf(vj.w - vj.y, 0.0f);
    int i = rb * 64 + lane;
    float4 bi;
    if (i < KPRE) {
        bi = topBox[b * KPRE + i];
        float off = (float)topLabel[b * KPRE + i] * 10000.0f;
        bi.x += off; bi.y += off; bi.z += off; bi.w += off;
    } else {
        bi = make_float4(-3e37f, -3e37f, -3e37f, -3e37f);
    }
    float ai = fmaxf(bi.z - bi.x, 0.0f) * fmaxf(bi.w - bi.y, 0.0f);
    __syncthreads();
    unsigned long long myword = 0;
#pragma unroll 8
    for (int jj = 0; jj < 64; ++jj) {
        int jg = cb * 64 + jj;
        float4 bj = cob[jj];
        float ltx = fmaxf(bi.x, bj.x), lty = fmaxf(bi.y, bj.y);
        float rbx = fminf(bi.z, bj.z), rby = fminf(bi.w, bj.w);
        float wx = fmaxf(rbx - ltx, 0.0f), wy = fmaxf(rby - lty, 0.0f);
        float inter = wx * wy;
        float iou = inter / fmaxf(ai + car[jj] - inter, 1e-6f);
        bool pred = (iou > 0.5f) && (i < jg) && (i < KPRE) && (jg < KPRE);
        unsigned long long bal = __ballot(pred);     // bit <lane> = source i suppresses target jg
        if (lane == jj) myword = bal;
    }
    maskT[(((size_t)b * NCH + rb) * NCH + cb) * 64 + lane] = myword;
}

// ---------------- K6: ballot-based greedy NMS + output (1 wave/image) ----------------
__global__ __launch_bounds__(64) void k_nmsout(const unsigned long long* __restrict__ maskT,
                                               const uint32_t* __restrict__ validCount,
                                               const float4* __restrict__ topBox,
                                               const float* __restrict__ topScore,
                                               const int* __restrict__ topLabel,
                                               float* __restrict__ out) {
    __shared__ unsigned long long km[NCH];   // kept mask per chunk (uniform)
    __shared__ int pf[NCH + 1];
    int b = blockIdx.x, lane = threadIdx.x;
    int V = (int)validCount[b];
    if (lane < NCH) km[lane] = 0ull;
    __syncthreads();
    const unsigned long long* mtb = maskT + (size_t)b * NCH * NCH * 64;
    int count = 0;
    unsigned long long mt[NCH];
#pragma unroll
    for (int s = 0; s < NCH; ++s) mt[s] = mtb[((size_t)s * NCH + 0) * 64 + lane];
    for (int c = 0; c < NCH; ++c) {
        if (c * 64 >= V || count >= MAXDET) break;
        unsigned long long cur[NCH];
#pragma unroll
        for (int s = 0; s < NCH; ++s) cur[s] = mt[s];
        if (c + 1 < NCH) {
#pragma unroll
            for (int s = 0; s < NCH; ++s) mt[s] = mtb[((size_t)s * NCH + (c + 1)) * 64 + lane];
        }
        unsigned long long dd = 0;
        unsigned long long colbits = 0;
#pragma unroll
        for (int s = 0; s < NCH; ++s) {
            if (s == c) colbits = cur[s];
            dd |= (cur[s] & km[s]);
        }
        bool dead = dd != 0ull;
        bool valid = (c * 64 + lane) < V;
        bool kept = false;
        unsigned long long kmask = 0;
        while (count < MAXDET) {
            unsigned long long undec = __ballot((!dead) && (!kept) && valid);
            if (undec == 0ull) break;
            int f = __builtin_ctzll(undec);     // lowest index = next greedy keep
            kmask |= 1ull << f;
            ++count;
            if (lane == f) kept = true;
            dead = dead || (((colbits >> f) & 1ull) != 0ull);
        }
        if (lane == 0) km[c] = kmask;
        __syncthreads();
    }
    __syncthreads();
    if (lane == 0) {
        int acc = 0;
        for (int cc = 0; cc < NCH; ++cc) { pf[cc] = acc; acc += __popcll(km[cc]); }
        pf[NCH] = acc;
    }
    __syncthreads();
    int total = pf[NCH];
    for (int cc = 0; cc < NCH; ++cc) {
        unsigned long long m = km[cc];
        if ((m >> lane) & 1ull) {
            int slot = pf[cc] + __popcll(m & ((1ull << lane) - 1ull));
            int g = cc * 64 + lane;
            int tdx = b * MAXDET + slot;
            float4 box = topBox[b * KPRE + g];
            out[(size_t)tdx * 4 + 0] = box.x;
            out[(size_t)tdx * 4 + 1] = box.y;
            out[(size_t)tdx * 4 + 2] = box.z;
            out[(size_t)tdx * 4 + 3] = box.w;
            out[(size_t)NB * MAXDET * 4 + tdx] = topScore[b * KPRE + g];
            out[(size_t)NB * MAXDET * 5 + tdx] = (float)(topLabel[b * KPRE + g] + 1);
        }
    }
    for (int k = lane; k < MAXDET; k += 64) {
        if (k >= total) {
            int tdx = b * MAXDET + k;
            out[(size_t)tdx * 4 + 0] = 0.0f;
            out[(size_t)tdx * 4 + 1] = 0.0f;
            out[(size_t)tdx * 4 + 2] = 0.0f;
            out[(size_t)tdx * 4 + 3] = 0.0f;
            out[(size_t)NB * MAXDET * 4 + tdx] = 0.0f;
            out[(size_t)NB * MAXDET * 5 + tdx] = 0.0f;
        }
    }
}

extern "C" void kernel_launch(void* const* d_in, const int* in_sizes, int n_in,
                              void* d_out, int out_size, void* d_ws, size_t ws_size,
                              hipStream_t stream) {
    const float* cls = (const float*)d_in[0];
    const float* boxp = (const float*)d_in[1];
    const float* anchors = (const float*)d_in[2];
    float* out = (float*)d_out;

    char* wsp = (char*)d_ws;
    size_t off = 0;
    auto carve = [&](size_t bytes) -> void* {
        void* p = wsp + off;
        off += (bytes + 255) & ~(size_t)255;
        return p;
    };
    unsigned long long* maskT = (unsigned long long*)carve((size_t)NB * NCH * NCH * 64 * 8);
    uint32_t* key       = (uint32_t*)carve((size_t)NB * AANCH * 4);
    int*      label     = (int*)carve((size_t)NB * AANCH * 4);
    uint32_t* candKey   = (uint32_t*)carve((size_t)NB * CANDCAP * 4);
    uint32_t* candIdx   = (uint32_t*)carve((size_t)NB * CANDCAP * 4);
    float4*   topBox    = (float4*)carve((size_t)NB * KPRE * 16);
    uint32_t* topKey    = (uint32_t*)carve((size_t)NB * KPRE * 4);
    uint32_t* topIdx    = (uint32_t*)carve((size_t)NB * KPRE * 4);
    float*    topScore  = (float*)carve((size_t)NB * KPRE * 4);
    int*      topLabel  = (int*)carve((size_t)NB * KPRE * 4);
    uint32_t* validCnt  = (uint32_t*)carve((size_t)NB * 4);
    uint32_t* candCount = (uint32_t*)carve((size_t)NB * 4);
    (void)ws_size; (void)out_size; (void)n_in; (void)in_sizes;

    k_score<<<dim3(AANCH / 64, NB), 256, 0, stream>>>(cls, key, label);
    k_fsel<<<NB, 1024, 0, stream>>>(key, validCnt, candCount, candKey, candIdx);
    k_rank<<<dim3(CANDCAP / 256, NB), 256, 0, stream>>>(candKey, candIdx, candCount,
                                                        topKey, topIdx);
    k_gather<<<(NB * KPRE + 255) / 256, 256, 0, stream>>>(topKey, topIdx, label, boxp, anchors,
                                                          topBox, topScore, topLabel);
    k_maskT<<<dim3(136, NB), 64, 0, stream>>>(topBox, topLabel, maskT);
    k_nmsout<<<NB, 64, 0, stream>>>(maskT, validCnt, topBox, topScore, topLabel, out);
}

// Round 5
// 217.078 us; speedup vs baseline: 2.4246x; 1.0971x over previous
//
#include <hip/hip_runtime.h>
#include <cstdint>
#include <cmath>

#define NB 16
#define AANCH 16320
#define NCLS 80
#define KPRE 1000
#define MAXDET 300
#define NCH 16            // 16 chunks of 64 >= 1000 candidates
#define CANDCAP 16384
#define HBINS 8192

// logit(0.05)
#define THR_LOGIT -2.9444389791664403f

// ---------------- K1: streaming max/argmax, 4 lanes per anchor, no LDS ----------------
__global__ __launch_bounds__(256) void k_score(const float* __restrict__ cls,
                                               uint32_t* __restrict__ key,
                                               int* __restrict__ label) {
    int b = blockIdx.y;
    int a0 = blockIdx.x * 64;
    int t = threadIdx.x;
    int al = t >> 2, g = t & 3;               // 4 lanes per anchor
    const float4* p = (const float4*)(cls + ((size_t)b * AANCH + a0) * NCLS) + al * 20 + g;
    float best = -3e38f; int bi = 0;
#pragma unroll
    for (int i = 0; i < 5; ++i) {             // classes c = 4g + 16i + e (ascending per thread)
        float4 v = p[4 * i];
        int c0 = 4 * g + 16 * i;
        if (v.x > best) { best = v.x; bi = c0 + 0; }
        if (v.y > best) { best = v.y; bi = c0 + 1; }
        if (v.z > best) { best = v.z; bi = c0 + 2; }
        if (v.w > best) { best = v.w; bi = c0 + 3; }
    }
#pragma unroll
    for (int m = 1; m <= 2; m <<= 1) {        // reduce 4-lane group, first-max (lowest class) wins
        float ob = __shfl_xor(best, m, 64);
        int oi = __shfl_xor(bi, m, 64);
        if (ob > best || (ob == best && oi < bi)) { best = ob; bi = oi; }
    }
    if (g == 0) {
        uint32_t k = 0;
        if (best > THR_LOGIT) {
            uint32_t ub = __float_as_uint(best);
            k = (ub & 0x80000000u) ? ~ub : (ub | 0x80000000u);  // order-preserving map
        }
        int ag = a0 + al;
        key[(size_t)b * AANCH + ag] = k;
        label[(size_t)b * AANCH + ag] = bi;
    }
}

// ------- K2: fused per-image hist + pivot + compaction (keys staged in LDS) -------
__global__ __launch_bounds__(1024) void k_fsel(const uint32_t* __restrict__ key,
                                               uint32_t* __restrict__ validCount,
                                               uint32_t* __restrict__ candCount,
                                               uint32_t* __restrict__ candKey,
                                               uint32_t* __restrict__ candIdx) {
    __shared__ uint32_t kk[AANCH];     // 65280 B
    __shared__ uint32_t hist[HBINS];   // 32768 B
    __shared__ uint32_t part[256];
    __shared__ uint32_t s_pivot, s_pos;
    int b = blockIdx.x, tid = threadIdx.x;
    for (int i = tid; i < HBINS; i += 1024) hist[i] = 0;
    if (tid == 0) s_pos = 0;
    __syncthreads();
    const uint32_t* kb = key + (size_t)b * AANCH;
    for (int i = tid; i < AANCH; i += 1024) {
        uint32_t k = kb[i];
        kk[i] = k;
        atomicAdd(&hist[k >> 19], 1u);
    }
    __syncthreads();
    if (tid < 256) {
        uint32_t s = 0;
#pragma unroll
        for (int i = 0; i < 32; ++i) s += hist[tid * 32 + ((i + tid) & 31)];  // 2-way only
        part[tid] = s;
    }
    __syncthreads();
    if (tid == 0) {
        uint32_t acc = 0; int tc = 0;
        for (int t2 = 255; t2 >= 0; --t2) {
            if (acc + part[t2] >= (uint32_t)KPRE) { tc = t2; break; }
            acc += part[t2];
        }
        uint32_t p1 = 0;
        for (int bin = tc * 32 + 31; bin >= tc * 32; --bin) {
            if (acc + hist[bin] >= (uint32_t)KPRE) { p1 = (uint32_t)bin; break; }
            acc += hist[bin];
        }
        s_pivot = p1;
        uint32_t nvalid = (uint32_t)AANCH - hist[0];   // bin 0 holds exactly key==0 entries
        validCount[b] = nvalid < (uint32_t)KPRE ? nvalid : (uint32_t)KPRE;
    }
    __syncthreads();
    uint32_t piv = s_pivot;
    for (int i = tid; i < AANCH; i += 1024) {
        uint32_t k = kk[i];
        if ((k >> 19) >= piv) {
            uint32_t pos = atomicAdd(&s_pos, 1u);
            if (pos < CANDCAP) {
                candKey[(size_t)b * CANDCAP + pos] = k;
                candIdx[(size_t)b * CANDCAP + pos] = (uint32_t)i;
            }
        }
    }
    __syncthreads();
    if (tid == 0) candCount[b] = s_pos < CANDCAP ? s_pos : CANDCAP;
}

// ------- K3: exact rank (packed u64 compare) + decode, fused ----------
// rank condition (key desc, idx asc) == packed (key<<32 | ~idx) descending
__global__ __launch_bounds__(256) void k_rankdec(const uint32_t* __restrict__ candKey,
                                                 const uint32_t* __restrict__ candIdx,
                                                 const uint32_t* __restrict__ candCount,
                                                 const int* __restrict__ label,
                                                 const float* __restrict__ boxp,
                                                 const float* __restrict__ anchors,
                                                 float4* __restrict__ topBox,
                                                 float* __restrict__ topScore,
                                                 int* __restrict__ topLabel) {
    __shared__ unsigned long long tp[2048];
    int b = blockIdx.y, tid = threadIdx.x;
    int C = (int)candCount[b];
    if (blockIdx.x * 256 >= C) return;
    const uint32_t* ck = candKey + (size_t)b * CANDCAP;
    const uint32_t* ci = candIdx + (size_t)b * CANDCAP;
    int c = blockIdx.x * 256 + tid;
    bool h = c < C;
    uint32_t mk = 0, mi = 0;
    if (h) { mk = ck[c]; mi = ci[c]; }
    unsigned long long mine = ((unsigned long long)mk << 32) | (uint32_t)(~mi);
    uint32_t r = 0;
    for (int t0 = 0; t0 < C; t0 += 2048) {
        int n = C - t0; if (n > 2048) n = 2048;
        __syncthreads();
        for (int j = tid; j < n; j += 256)
            tp[j] = ((unsigned long long)ck[t0 + j] << 32) | (uint32_t)(~ci[t0 + j]);
        __syncthreads();
#pragma unroll 4
        for (int j = 0; j < n; ++j) r += (tp[j] > mine);
    }
    if (!h || r >= (uint32_t)KPRE) return;
    // ---- decode ----
    uint32_t idx = mi;
    const float* an = anchors + (size_t)idx * 4;
    float a0 = an[0], a1 = an[1], a2 = an[2], a3 = an[3];
    const float* dp = boxp + ((size_t)b * AANCH + idx) * 4;
    float d0 = dp[0], d1 = dp[1], d2 = dp[2], d3 = dp[3];
    float aw = a2 - a0, ah = a3 - a1;
    float acx = a0 + 0.5f * aw, acy = a1 + 0.5f * ah;
    float cx = d0 * aw + acx, cy = d1 * ah + acy;
    float w = expf(d2) * aw, hh = expf(d3) * ah;
    float x1 = fminf(fmaxf(cx - 0.5f * w, 0.0f), 512.0f);
    float y1 = fminf(fmaxf(cy - 0.5f * hh, 0.0f), 512.0f);
    float x2 = fminf(fmaxf(cx + 0.5f * w, 0.0f), 512.0f);
    float y2 = fminf(fmaxf(cy + 0.5f * hh, 0.0f), 512.0f);
    float score;
    if (mk == 0u) {
        score = -1.0f;
    } else {
        uint32_t ub = (mk & 0x80000000u) ? (mk ^ 0x80000000u) : ~mk;
        score = 1.0f / (1.0f + expf(-__uint_as_float(ub)));
    }
    int t = b * KPRE + (int)r;
    topBox[t] = make_float4(x1, y1, x2, y2);
    topScore[t] = score;
    topLabel[t] = label[(size_t)b * AANCH + idx];
}

// ---------------- K4: TRANSPOSED suppression mask via ballot ----------------
// MT[((b*NCH + srcChunk)*NCH + tgtChunk)*64 + j] : bit i = "cand srcChunk*64+i suppresses cand tgtChunk*64+j"
__global__ __launch_bounds__(64) void k_maskT(const float4* __restrict__ topBox,
                                              const int* __restrict__ topLabel,
                                              unsigned long long* __restrict__ maskT) {
    int b = blockIdx.y;
    int tt = blockIdx.x;                 // 0..135 triangular -> (rb<=cb)
    int rb = 0;
    while (tt >= NCH - rb) { tt -= NCH - rb; ++rb; }
    int cb = rb + tt;
    __shared__ float4 cob[64];
    __shared__ float car[64];
    int lane = threadIdx.x;
    int j = cb * 64 + lane;
    float4 vj;
    if (j < KPRE) {
        vj = topBox[b * KPRE + j];
        float off = (float)topLabel[b * KPRE + j] * 10000.0f;
        vj.x += off; vj.y += off; vj.z += off; vj.w += off;
    } else {
        vj = make_float4(-3e37f, -3e37f, -3e37f, -3e37f);
    }
    cob[lane] = vj;
    car[lane] = fmaxf(vj.z - vj.x, 0.0f) * fmaxf(vj.w - vj.y, 0.0f);
    int i = rb * 64 + lane;
    float4 bi;
    if (i < KPRE) {
        bi = topBox[b * KPRE + i];
        float off = (float)topLabel[b * KPRE + i] * 10000.0f;
        bi.x += off; bi.y += off; bi.z += off; bi.w += off;
    } else {
        bi = make_float4(-3e37f, -3e37f, -3e37f, -3e37f);
    }
    float ai = fmaxf(bi.z - bi.x, 0.0f) * fmaxf(bi.w - bi.y, 0.0f);
    __syncthreads();
    unsigned long long myword = 0;
#pragma unroll 8
    for (int jj = 0; jj < 64; ++jj) {
        int jg = cb * 64 + jj;
        float4 bj = cob[jj];
        float ltx = fmaxf(bi.x, bj.x), lty = fmaxf(bi.y, bj.y);
        float rbx = fminf(bi.z, bj.z), rby = fminf(bi.w, bj.w);
        float wx = fmaxf(rbx - ltx, 0.0f), wy = fmaxf(rby - lty, 0.0f);
        float inter = wx * wy;
        float iou = inter / fmaxf(ai + car[jj] - inter, 1e-6f);
        bool pred = (iou > 0.5f) && (i < jg) && (i < KPRE) && (jg < KPRE);
        unsigned long long bal = __ballot(pred);     // bit <lane> = source i suppresses target jg
        if (lane == jj) myword = bal;
    }
    maskT[(((size_t)b * NCH + rb) * NCH + cb) * 64 + lane] = myword;
}

// ---------------- K5: ballot-based greedy NMS + output (1 wave/image) ----------------
__global__ __launch_bounds__(64) void k_nmsout(const unsigned long long* __restrict__ maskT,
                                               const uint32_t* __restrict__ validCount,
                                               const float4* __restrict__ topBox,
                                               const float* __restrict__ topScore,
                                               const int* __restrict__ topLabel,
                                               float* __restrict__ out) {
    __shared__ unsigned long long km[NCH];   // kept mask per chunk (uniform)
    __shared__ int pf[NCH + 1];
    int b = blockIdx.x, lane = threadIdx.x;
    int V = (int)validCount[b];
    if (lane < NCH) km[lane] = 0ull;
    __syncthreads();
    const unsigned long long* mtb = maskT + (size_t)b * NCH * NCH * 64;
    int count = 0;
    unsigned long long mt[NCH];
#pragma unroll
    for (int s = 0; s < NCH; ++s) mt[s] = mtb[((size_t)s * NCH + 0) * 64 + lane];
    for (int c = 0; c < NCH; ++c) {
        if (c * 64 >= V || count >= MAXDET) break;
        unsigned long long cur[NCH];
#pragma unroll
        for (int s = 0; s < NCH; ++s) cur[s] = mt[s];
        if (c + 1 < NCH) {
#pragma unroll
            for (int s = 0; s < NCH; ++s) mt[s] = mtb[((size_t)s * NCH + (c + 1)) * 64 + lane];
        }
        unsigned long long dd = 0;
        unsigned long long colbits = 0;
#pragma unroll
        for (int s = 0; s < NCH; ++s) {
            if (s == c) colbits = cur[s];
            dd |= (cur[s] & km[s]);
        }
        bool dead = dd != 0ull;
        bool valid = (c * 64 + lane) < V;
        bool kept = false;
        unsigned long long kmask = 0;
        while (count < MAXDET) {
            unsigned long long undec = __ballot((!dead) && (!kept) && valid);
            if (undec == 0ull) break;
            int f = __builtin_ctzll(undec);     // lowest index = next greedy keep
            kmask |= 1ull << f;
            ++count;
            if (lane == f) kept = true;
            dead = dead || (((colbits >> f) & 1ull) != 0ull);
        }
        if (lane == 0) km[c] = kmask;
        __syncthreads();
    }
    __syncthreads();
    if (lane == 0) {
        int acc = 0;
        for (int cc = 0; cc < NCH; ++cc) { pf[cc] = acc; acc += __popcll(km[cc]); }
        pf[NCH] = acc;
    }
    __syncthreads();
    int total = pf[NCH];
    for (int cc = 0; cc < NCH; ++cc) {
        unsigned long long m = km[cc];
        if ((m >> lane) & 1ull) {
            int slot = pf[cc] + __popcll(m & ((1ull << lane) - 1ull));
            int g = cc * 64 + lane;
            int tdx = b * MAXDET + slot;
            float4 box = topBox[b * KPRE + g];
            out[(size_t)tdx * 4 + 0] = box.x;
            out[(size_t)tdx * 4 + 1] = box.y;
            out[(size_t)tdx * 4 + 2] = box.z;
            out[(size_t)tdx * 4 + 3] = box.w;
            out[(size_t)NB * MAXDET * 4 + tdx] = topScore[b * KPRE + g];
            out[(size_t)NB * MAXDET * 5 + tdx] = (float)(topLabel[b * KPRE + g] + 1);
        }
    }
    for (int k = lane; k < MAXDET; k += 64) {
        if (k >= total) {
            int tdx = b * MAXDET + k;
            out[(size_t)tdx * 4 + 0] = 0.0f;
            out[(size_t)tdx * 4 + 1] = 0.0f;
            out[(size_t)tdx * 4 + 2] = 0.0f;
            out[(size_t)tdx * 4 + 3] = 0.0f;
            out[(size_t)NB * MAXDET * 4 + tdx] = 0.0f;
            out[(size_t)NB * MAXDET * 5 + tdx] = 0.0f;
        }
    }
}

extern "C" void kernel_launch(void* const* d_in, const int* in_sizes, int n_in,
                              void* d_out, int out_size, void* d_ws, size_t ws_size,
                              hipStream_t stream) {
    const float* cls = (const float*)d_in[0];
    const float* boxp = (const float*)d_in[1];
    const float* anchors = (const float*)d_in[2];
    float* out = (float*)d_out;

    char* wsp = (char*)d_ws;
    size_t off = 0;
    auto carve = [&](size_t bytes) -> void* {
        void* p = wsp + off;
        off += (bytes + 255) & ~(size_t)255;
        return p;
    };
    unsigned long long* maskT = (unsigned long long*)carve((size_t)NB * NCH * NCH * 64 * 8);
    uint32_t* key       = (uint32_t*)carve((size_t)NB * AANCH * 4);
    int*      label     = (int*)carve((size_t)NB * AANCH * 4);
    uint32_t* candKey   = (uint32_t*)carve((size_t)NB * CANDCAP * 4);
    uint32_t* candIdx   = (uint32_t*)carve((size_t)NB * CANDCAP * 4);
    float4*   topBox    = (float4*)carve((size_t)NB * KPRE * 16);
    float*    topScore  = (float*)carve((size_t)NB * KPRE * 4);
    int*      topLabel  = (int*)carve((size_t)NB * KPRE * 4);
    uint32_t* validCnt  = (uint32_t*)carve((size_t)NB * 4);
    uint32_t* candCount = (uint32_t*)carve((size_t)NB * 4);
    (void)ws_size; (void)out_size; (void)n_in; (void)in_sizes;

    k_score<<<dim3(AANCH / 64, NB), 256, 0, stream>>>(cls, key, label);
    k_fsel<<<NB, 1024, 0, stream>>>(key, validCnt, candCount, candKey, candIdx);
    k_rankdec<<<dim3(CANDCAP / 256, NB), 256, 0, stream>>>(candKey, candIdx, candCount, label,
                                                           boxp, anchors, topBox, topScore,
                                                           topLabel);
    k_maskT<<<dim3(136, NB), 64, 0, stream>>>(topBox, topLabel, maskT);
    k_nmsout<<<NB, 64, 0, stream>>>(maskT, validCnt, topBox, topScore, topLabel, out);
}